// Round 18
// baseline (41.298 us; speedup 1.0000x reference)
//
#include <hip/hip_runtime.h>

// Acrobot GN step — in-register kperm chaining widened to QUAD ROW-GROUPS acc[n<4][m]
// (64-row wave-tiles). R17 (dual groups, 32.0us) showed the remaining wall is LDS pipe
// (~13.4us/CU of weight-table re-reads). Each table fragment read now feeds 4 MFMAs,
// halving per-CU LDS traffic; per-tile latency amortizes over 2x work. ~250 regs,
// still 2 waves/SIMD.
//   G1: e1 = relu(A1 @ in32)                 32 MFMA (A1 frags from aLDS, shared n=0..3)
//   G2: e2 = relu(A2 @ e1 + be2)             128 MFMA (A2 from 32KB swizzled LDS)
//   G3: hdd = relu(A3 @ [e2[r^1]; sender,1]) 160 MFMA (A3 from 32KB swizzled LDS)
//   G4: delta = A4 @ relu(hdd) + bn2         16 MFMA (A4 kperm'd, from aLDS)
// No barriers in loop; LDS 74KB -> 2 blocks/CU; grid 512 x 256thr; 2 tiles/wave.

typedef __attribute__((ext_vector_type(8))) short bf16x8;
typedef __attribute__((ext_vector_type(4))) float f32x4;

union U4B { uint4 u; bf16x8 b; };

__device__ __forceinline__ unsigned short f2bf(float f) {
  union { float f; unsigned u; } v; v.f = f;
  return (unsigned short)((v.u + 0x7FFFu + ((v.u >> 16) & 1u)) >> 16);  // RNE
}

__device__ __forceinline__ unsigned cvtpk(float lo, float hi) {
  unsigned r;
  asm("v_cvt_pk_bf16_f32 %0, %1, %2" : "=v"(r) : "v"(lo), "v"(hi));
  return r;
}

// K-dim permutation matching the in-register accumulator packing:
// B element position k=(kk,gg,i) holds feature 32*kk + 16*(i>>2) + 4*gg + (i&3).
__host__ __device__ __forceinline__ int kperm(int k) {
  int kk = k >> 5, gg = (k >> 3) & 3, i = k & 7;
  return kk * 32 + (i >> 2) * 16 + gg * 4 + (i & 3);
}

// ---------------- weight prep (identical to R14/R17, verified) ----------------
// shorts: A1c [128j][8k] @0 ; A3e [128j][8k] @1024 ; A4 kperm [16][128] @2048 ;
//         A2 kperm @4096 ; A3 kperm @20480 ; be2 f32[128] @36864 (74240 B total).
__global__ void gn_prep(const float* __restrict__ We1, const float* __restrict__ be1,
                        const float* __restrict__ We2, const float* __restrict__ Wn1,
                        const float* __restrict__ bn1, const float* __restrict__ Wn2,
                        const float* __restrict__ be2,
                        unsigned short* __restrict__ wsA) {
  int t = blockIdx.x * 256 + threadIdx.x;
  if (t < 1024) {                       // A1 compact: k<7 -> We1 rows 10..16 ; k==7 -> be1
    int j = t >> 3, k = t & 7;
    wsA[t] = f2bf((k < 7) ? We1[(10 + k) * 128 + j] : be1[j]);
  } else if (t < 2048) {                // A3ext compact: c0=Wn1r10, c1=Wn1r11, c2=bn1
    int t2 = t - 1024; int j = t2 >> 3, c = t2 & 7;
    float v = (c == 0) ? Wn1[10 * 128 + j] : (c == 1) ? Wn1[11 * 128 + j]
            : (c == 2) ? bn1[j] : 0.0f;
    wsA[t] = f2bf(v);
  } else if (t < 4096) {                // A4 = Wn2^T padded [16][128], K-permuted
    int i = t - 2048; int jp = i >> 7, k = i & 127;
    wsA[t] = f2bf((jp < 2) ? Wn2[kperm(k) * 2 + jp] : 0.0f);
  } else if (t < 20480) {               // A2 = We2^T, K-permuted
    int t2 = t - 4096; int j = t2 >> 7, k = t2 & 127;
    wsA[t] = f2bf(We2[kperm(k) * 128 + j]);
  } else if (t < 36864) {               // A3 main = Wn1[12:140]^T, K-permuted
    int t2 = t - 20480; int j = t2 >> 7, k = t2 & 127;
    wsA[t] = f2bf(Wn1[(12 + kperm(k)) * 128 + j]);
  } else if (t < 36992) {               // be2 as f32
    ((float*)(wsA + 36864))[t - 36864] = be2[t - 36864];
  }
}

// ---------------- main fused kernel ----------------
#define WTILES 4096   // 262144 rows / 64 rows per wave-tile
#define NWAVES 2048   // 512 blocks x 4 waves; 2 tiles per wave

__global__ __launch_bounds__(256) __attribute__((amdgpu_waves_per_eu(2, 2)))
void gn_main(
    const float* __restrict__ x, const float* __restrict__ u,
    const float* __restrict__ nmean, const float* __restrict__ nstd,
    const float* __restrict__ emean, const float* __restrict__ estd,
    const float* __restrict__ bn2,
    const unsigned short* __restrict__ wsA,
    float* __restrict__ out)
{
  __shared__ __align__(16) unsigned short a2T[128 * 128];   // 32KB swizzled A2 table
  __shared__ __align__(16) unsigned short a3T[128 * 128];   // 32KB swizzled A3 table
  __shared__ __align__(16) unsigned short aLDS[4352];       // 8.5KB: A1c|A3e|A4|be2

  const int tid  = threadIdx.x;
  const int lane = tid & 63;
  const int wid  = tid >> 6;
  const int c15  = lane & 15;
  const int g    = lane >> 4;    // 0..3
  const int sw15 = (c15 & 7) << 4;

  // ---- build swizzled tables + compact tables in LDS (one time; verified pattern) ----
  for (int t = tid; t < 2048; t += 256) {
    int j = t >> 4, c = t & 15;
    uint4 v2 = *(const uint4*)(wsA + 4096 + j * 128 + c * 8);
    *(uint4*)((char*)a2T + j * 256 + ((c * 16) ^ ((j & 7) << 4))) = v2;
    uint4 v3 = *(const uint4*)(wsA + 20480 + j * 128 + c * 8);
    *(uint4*)((char*)a3T + j * 256 + ((c * 16) ^ ((j & 7) << 4))) = v3;
  }
  for (int t = tid; t < 2048; t += 256)       // A1c | A3e | A4  (ws shorts 0..4096)
    ((unsigned*)aLDS)[t] = ((const unsigned*)wsA)[t];
  for (int t = tid; t < 128; t += 256)        // be2 (128 f32) -> aLDS byte 8192
    ((unsigned*)aLDS)[2048 + t] = ((const unsigned*)(wsA + 36864))[t];

  const float nm0 = nmean[0], nm1 = nmean[1];
  const float is0 = 1.0f / nstd[0], is1 = 1.0f / nstd[1];
  const float em0 = emean[0], ie0 = 1.0f / estd[0];
  const float cea1 = (0.0f - emean[1]) / estd[1];
  const float cea2 = (0.0f - emean[2]) / estd[2];
  const float bn20 = bn2[0], bn21 = bn2[1];
  const unsigned cpkw = cvtpk(cea2, 1.0f);   // B dword3: [cea2, 1.0]

  // ---- prefetch first tile's x/u (rows rowbase + n*16 + c15, n=0..3) ----
  float4 xv[4]; float uv[4];
  #pragma unroll
  for (int n = 0; n < 4; ++n) { xv[n] = (float4){0.f,0.f,0.f,0.f}; uv[n] = 0.f; }
  if (g == 0) {
    int w0 = blockIdx.x * 4 + wid;
    #pragma unroll
    for (int n = 0; n < 4; ++n) {
      int b = w0 * 32 + n * 8 + (c15 >> 1);
      xv[n] = *(const float4*)(x + b * 4);
      uv[n] = u[b];
    }
  }

  auto buildB = [&](const float4& xv_, float uv_, unsigned& pks_, bf16x8& Bv_,
                    float& xs0_, float& xs1_) {
    xs0_ = (c15 & 1) ? xv_.y : xv_.x;   // this row's raw theta
    xs1_ = (c15 & 1) ? xv_.w : xv_.z;   // this row's raw v
    uint4 bu = (uint4){0u, 0u, 0u, 0u};
    if (g == 0) {                       // only k=0..7 nonzero; g==0 lanes hold them
      float a0 = (xv_.x - nm0) * is0, a1 = (xv_.z - nm1) * is1;   // node0
      float b0 = (xv_.y - nm0) * is0, b1 = (xv_.w - nm1) * is1;   // node1
      bool  e  = (c15 & 1);
      float s0 = e ? b0 : a0, s1 = e ? b1 : a1;   // sender feats
      float r0 = e ? a0 : b0, r1 = e ? a1 : b1;   // receiver feats
      float ea0 = (uv_ - em0) * ie0;
      bu.x = cvtpk(s0, s1); bu.y = cvtpk(r0, r1);
      bu.z = cvtpk(ea0, cea1); bu.w = cpkw;
    }
    pks_ = bu.x;
    U4B t; t.u = bu; Bv_ = t.b;
  };

  auto packE = [&](const f32x4 (&a)[8], bf16x8 (&E)[4]) {
    #pragma unroll
    for (int kk = 0; kk < 4; ++kk) {
      f32x4 a0 = a[2 * kk], a1 = a[2 * kk + 1];
      uint4 e;
      e.x = cvtpk(fmaxf(a0[0], 0.f), fmaxf(a0[1], 0.f));
      e.y = cvtpk(fmaxf(a0[2], 0.f), fmaxf(a0[3], 0.f));
      e.z = cvtpk(fmaxf(a1[0], 0.f), fmaxf(a1[1], 0.f));
      e.w = cvtpk(fmaxf(a1[2], 0.f), fmaxf(a1[3], 0.f));
      U4B t; t.u = e; E[kk] = t.b;
    }
  };
  auto packEswap = [&](const f32x4 (&a)[8], bf16x8 (&E)[4]) {
    #pragma unroll
    for (int kk = 0; kk < 4; ++kk) {
      f32x4 a0 = a[2 * kk], a1 = a[2 * kk + 1];
      uint4 e;
      e.x = __shfl_xor(cvtpk(fmaxf(a0[0], 0.f), fmaxf(a0[1], 0.f)), 1, 64);
      e.y = __shfl_xor(cvtpk(fmaxf(a0[2], 0.f), fmaxf(a0[3], 0.f)), 1, 64);
      e.z = __shfl_xor(cvtpk(fmaxf(a1[0], 0.f), fmaxf(a1[1], 0.f)), 1, 64);
      e.w = __shfl_xor(cvtpk(fmaxf(a1[2], 0.f), fmaxf(a1[3], 0.f)), 1, 64);
      U4B t; t.u = e; E[kk] = t.b;
    }
  };

  __syncthreads();   // tables ready — the only barrier

  for (int wt = blockIdx.x * 4 + wid; wt < WTILES; wt += NWAVES) {
    const int rowbase = wt * 64;

    // opaque LDS offset: stop LICM from hoisting table reads into (spilling) registers
    unsigned aoff = 0;
    asm volatile("" : "+v"(aoff));
    const char* aB  = (const char*)aLDS + aoff;
    const char* a2B = (const char*)a2T + aoff;
    const char* a3B = (const char*)a3T + aoff;

    // ---------- build B-operands for all 4 row-groups; save raw x for stores ----------
    unsigned pks[4]; bf16x8 Bv[4];
    float xs0[4], xs1[4];
    #pragma unroll
    for (int n = 0; n < 4; ++n)
      buildB(xv[n], uv[n], pks[n], Bv[n], xs0[n], xs1[n]);

    // ---------- prefetch next tile's x/u ----------
    {
      int nt = wt + NWAVES;
      if (g == 0 && nt < WTILES) {
        #pragma unroll
        for (int n = 0; n < 4; ++n) {
          int b = nt * 32 + n * 8 + (c15 >> 1);
          xv[n] = *(const float4*)(x + b * 4);
          uv[n] = u[b];
        }
      }
    }

    f32x4 acc[4][8];

    // ---------- G1: e1 = relu(A1 @ in32); A1 frag shared across n ----------
    #pragma unroll
    for (int m = 0; m < 8; ++m) {
      U4B ta; ta.u = *(const uint4*)(aB + (m * 16 + c15) * 16);   // A1 frag
      #pragma unroll
      for (int n = 0; n < 4; ++n) {
        f32x4 z = (f32x4){0.f, 0.f, 0.f, 0.f};
        acc[n][m] = __builtin_amdgcn_mfma_f32_16x16x32_bf16(ta.b, Bv[n], z, 0, 0, 0);
      }
    }
    bf16x8 E1[4][4];
    #pragma unroll
    for (int n = 0; n < 4; ++n) packE(acc[n], E1[n]);

    // ---------- G2: e2 = relu(A2 @ e1 + be2); A2 from LDS, shared across n ----------
    #pragma unroll
    for (int m = 0; m < 8; ++m) {
      f32x4 bz = *(const f32x4*)(aB + 8192 + (m * 16 + g * 4) * 4);
      #pragma unroll
      for (int n = 0; n < 4; ++n) acc[n][m] = bz;
    }
    #pragma unroll
    for (int kk = 0; kk < 4; ++kk)
      #pragma unroll
      for (int m = 0; m < 8; ++m) {
        U4B tf; tf.u = *(const uint4*)(a2B + (m * 16 + c15) * 256 + ((kk * 64 + g * 16) ^ sw15));
        #pragma unroll
        for (int n = 0; n < 4; ++n)
          acc[n][m] = __builtin_amdgcn_mfma_f32_16x16x32_bf16(tf.b, E1[n][kk], acc[n][m], 0, 0, 0);
      }
    bf16x8 E2[4][4];
    #pragma unroll
    for (int n = 0; n < 4; ++n) packEswap(acc[n], E2[n]);

    // ---------- G3: hdd = relu(A3 @ [e2[r^1]; sender,1]); A3 from LDS, shared ----------
    #pragma unroll
    for (int m = 0; m < 8; ++m)
      #pragma unroll
      for (int n = 0; n < 4; ++n)
        acc[n][m] = (f32x4){0.f, 0.f, 0.f, 0.f};
    #pragma unroll
    for (int kk = 0; kk < 4; ++kk)
      #pragma unroll
      for (int m = 0; m < 8; ++m) {
        U4B tf; tf.u = *(const uint4*)(a3B + (m * 16 + c15) * 256 + ((kk * 64 + g * 16) ^ sw15));
        #pragma unroll
        for (int n = 0; n < 4; ++n)
          acc[n][m] = __builtin_amdgcn_mfma_f32_16x16x32_bf16(tf.b, E2[n][kk], acc[n][m], 0, 0, 0);
      }
    {
      // K-chunk 4: node feats (= sender feats) + const-1 (bn1 column); A3e shared
      U4B t4[4];
      #pragma unroll
      for (int n = 0; n < 4; ++n) {
        uint4 b4 = (uint4){0u, 0u, 0u, 0u};
        if (g == 0) { b4.x = pks[n]; b4.y = 0x00003F80u; }
        t4[n].u = b4;
      }
      #pragma unroll
      for (int m = 0; m < 8; ++m) {
        U4B te; te.u = *(const uint4*)(aB + 2048 + (m * 16 + c15) * 16);  // A3e frag
        #pragma unroll
        for (int n = 0; n < 4; ++n)
          acc[n][m] = __builtin_amdgcn_mfma_f32_16x16x32_bf16(te.b, t4[n].b, acc[n][m], 0, 0, 0);
      }
    }

    // ---------- G4: delta = A4 @ relu(hdd) + bn2; A4 from aLDS (4 reads, shared) ----------
    {
      bf16x8 A4f[4];
      #pragma unroll
      for (int kk = 0; kk < 4; ++kk) {
        U4B ta; ta.u = *(const uint4*)(aB + 4096 + c15 * 256 + kk * 64 + g * 16);
        A4f[kk] = ta.b;
      }
      #pragma unroll
      for (int n = 0; n < 4; ++n) {
        bf16x8 HD[4];
        packE(acc[n], HD);
        f32x4 a4 = (f32x4){0.f, 0.f, 0.f, 0.f};
        #pragma unroll
        for (int kk = 0; kk < 4; ++kk)
          a4 = __builtin_amdgcn_mfma_f32_16x16x32_bf16(A4f[kk], HD[kk], a4, 0, 0, 0);
        if (g == 0) {                  // lane holds delta c0,c1 for row rowbase+n*16+c15
          int gr = rowbase + n * 16 + c15;
          int bidx = gr >> 1, k = gr & 1;
          out[bidx * 4 + k]     = xs0[n] + a4[0] + bn20;
          out[bidx * 4 + k + 2] = xs1[n] + a4[1] + bn21;
        }
      }
    }
    // no barrier: LDS tables are read-only after init; all activations in registers.
  }
}

extern "C" void kernel_launch(void* const* d_in, const int* in_sizes, int n_in,
                              void* d_out, int out_size, void* d_ws, size_t ws_size,
                              hipStream_t stream) {
  const float* x   = (const float*)d_in[0];
  const float* u   = (const float*)d_in[1];
  const float* nm  = (const float*)d_in[2];
  const float* ns  = (const float*)d_in[3];
  const float* em  = (const float*)d_in[4];
  const float* es  = (const float*)d_in[5];
  const float* We1 = (const float*)d_in[6];
  const float* be1 = (const float*)d_in[7];
  const float* We2 = (const float*)d_in[8];
  const float* be2 = (const float*)d_in[9];
  const float* Wn1 = (const float*)d_in[10];
  const float* bn1 = (const float*)d_in[11];
  const float* Wn2 = (const float*)d_in[12];
  const float* bn2 = (const float*)d_in[13];
  unsigned short* wsA = (unsigned short*)d_ws;   // needs 74240 bytes
  float* out = (float*)d_out;

  gn_prep<<<145, 256, 0, stream>>>(We1, be1, We2, Wn1, bn1, Wn2, be2, wsA);
  gn_main<<<512, 256, 0, stream>>>(x, u, nm, ns, em, es, bn2, wsA, out);
}

// Round 19
// 32.004 us; speedup vs baseline: 1.2904x; 1.2904x over previous
//
#include <hip/hip_runtime.h>

// Acrobot GN step — QUAD ROW-GROUPS acc[n<4][m] (64-row wave-tiles), register-trimmed.
// R18 post-mortem: quad-row spilled (~260 live regs; FETCH 11.5MB of scratch reloads).
// The ~20 loop-carried x/u prefetch registers were the overflow. R19: identical math,
// but x/u loads are TILE-LOCAL (die after B-build) and no cross-tile prefetch
// (<=0.75us/wave exposed latency vs ~7us/CU LDS savings). Peak live ~230 regs.
//   G1: e1 = relu(A1 @ in32)                 32 MFMA (A1 frags from aLDS, shared n=0..3)
//   G2: e2 = relu(A2 @ e1 + be2)             128 MFMA (A2 from 32KB swizzled LDS)
//   G3: hdd = relu(A3 @ [e2[r^1]; sender,1]) 160 MFMA (A3 from 32KB swizzled LDS)
//   G4: delta = A4 @ relu(hdd) + bn2         16 MFMA (A4 kperm'd, from aLDS)
// No barriers in loop; LDS 74KB -> 2 blocks/CU; grid 512 x 256thr; 2 tiles/wave.

typedef __attribute__((ext_vector_type(8))) short bf16x8;
typedef __attribute__((ext_vector_type(4))) float f32x4;

union U4B { uint4 u; bf16x8 b; };

__device__ __forceinline__ unsigned short f2bf(float f) {
  union { float f; unsigned u; } v; v.f = f;
  return (unsigned short)((v.u + 0x7FFFu + ((v.u >> 16) & 1u)) >> 16);  // RNE
}

__device__ __forceinline__ unsigned cvtpk(float lo, float hi) {
  unsigned r;
  asm("v_cvt_pk_bf16_f32 %0, %1, %2" : "=v"(r) : "v"(lo), "v"(hi));
  return r;
}

// K-dim permutation matching the in-register accumulator packing:
// B element position k=(kk,gg,i) holds feature 32*kk + 16*(i>>2) + 4*gg + (i&3).
__host__ __device__ __forceinline__ int kperm(int k) {
  int kk = k >> 5, gg = (k >> 3) & 3, i = k & 7;
  return kk * 32 + (i >> 2) * 16 + gg * 4 + (i & 3);
}

// ---------------- weight prep (identical to R14/R17, verified) ----------------
// shorts: A1c [128j][8k] @0 ; A3e [128j][8k] @1024 ; A4 kperm [16][128] @2048 ;
//         A2 kperm @4096 ; A3 kperm @20480 ; be2 f32[128] @36864 (74240 B total).
__global__ void gn_prep(const float* __restrict__ We1, const float* __restrict__ be1,
                        const float* __restrict__ We2, const float* __restrict__ Wn1,
                        const float* __restrict__ bn1, const float* __restrict__ Wn2,
                        const float* __restrict__ be2,
                        unsigned short* __restrict__ wsA) {
  int t = blockIdx.x * 256 + threadIdx.x;
  if (t < 1024) {                       // A1 compact: k<7 -> We1 rows 10..16 ; k==7 -> be1
    int j = t >> 3, k = t & 7;
    wsA[t] = f2bf((k < 7) ? We1[(10 + k) * 128 + j] : be1[j]);
  } else if (t < 2048) {                // A3ext compact: c0=Wn1r10, c1=Wn1r11, c2=bn1
    int t2 = t - 1024; int j = t2 >> 3, c = t2 & 7;
    float v = (c == 0) ? Wn1[10 * 128 + j] : (c == 1) ? Wn1[11 * 128 + j]
            : (c == 2) ? bn1[j] : 0.0f;
    wsA[t] = f2bf(v);
  } else if (t < 4096) {                // A4 = Wn2^T padded [16][128], K-permuted
    int i = t - 2048; int jp = i >> 7, k = i & 127;
    wsA[t] = f2bf((jp < 2) ? Wn2[kperm(k) * 2 + jp] : 0.0f);
  } else if (t < 20480) {               // A2 = We2^T, K-permuted
    int t2 = t - 4096; int j = t2 >> 7, k = t2 & 127;
    wsA[t] = f2bf(We2[kperm(k) * 128 + j]);
  } else if (t < 36864) {               // A3 main = Wn1[12:140]^T, K-permuted
    int t2 = t - 20480; int j = t2 >> 7, k = t2 & 127;
    wsA[t] = f2bf(Wn1[(12 + kperm(k)) * 128 + j]);
  } else if (t < 36992) {               // be2 as f32
    ((float*)(wsA + 36864))[t - 36864] = be2[t - 36864];
  }
}

// ---------------- main fused kernel ----------------
#define WTILES 4096   // 262144 rows / 64 rows per wave-tile
#define NWAVES 2048   // 512 blocks x 4 waves; 2 tiles per wave

__global__ __launch_bounds__(256) __attribute__((amdgpu_waves_per_eu(2, 2)))
void gn_main(
    const float* __restrict__ x, const float* __restrict__ u,
    const float* __restrict__ nmean, const float* __restrict__ nstd,
    const float* __restrict__ emean, const float* __restrict__ estd,
    const float* __restrict__ bn2,
    const unsigned short* __restrict__ wsA,
    float* __restrict__ out)
{
  __shared__ __align__(16) unsigned short a2T[128 * 128];   // 32KB swizzled A2 table
  __shared__ __align__(16) unsigned short a3T[128 * 128];   // 32KB swizzled A3 table
  __shared__ __align__(16) unsigned short aLDS[4352];       // 8.5KB: A1c|A3e|A4|be2

  const int tid  = threadIdx.x;
  const int lane = tid & 63;
  const int wid  = tid >> 6;
  const int c15  = lane & 15;
  const int g    = lane >> 4;    // 0..3
  const int sw15 = (c15 & 7) << 4;

  // ---- build swizzled tables + compact tables in LDS (one time; verified pattern) ----
  for (int t = tid; t < 2048; t += 256) {
    int j = t >> 4, c = t & 15;
    uint4 v2 = *(const uint4*)(wsA + 4096 + j * 128 + c * 8);
    *(uint4*)((char*)a2T + j * 256 + ((c * 16) ^ ((j & 7) << 4))) = v2;
    uint4 v3 = *(const uint4*)(wsA + 20480 + j * 128 + c * 8);
    *(uint4*)((char*)a3T + j * 256 + ((c * 16) ^ ((j & 7) << 4))) = v3;
  }
  for (int t = tid; t < 2048; t += 256)       // A1c | A3e | A4  (ws shorts 0..4096)
    ((unsigned*)aLDS)[t] = ((const unsigned*)wsA)[t];
  for (int t = tid; t < 128; t += 256)        // be2 (128 f32) -> aLDS byte 8192
    ((unsigned*)aLDS)[2048 + t] = ((const unsigned*)(wsA + 36864))[t];

  const float nm0 = nmean[0], nm1 = nmean[1];
  const float is0 = 1.0f / nstd[0], is1 = 1.0f / nstd[1];
  const float em0 = emean[0], ie0 = 1.0f / estd[0];
  const float cea1 = (0.0f - emean[1]) / estd[1];
  const float cea2 = (0.0f - emean[2]) / estd[2];
  const float bn20 = bn2[0], bn21 = bn2[1];
  const unsigned cpkw = cvtpk(cea2, 1.0f);   // B dword3: [cea2, 1.0]

  // tile-local B build: loads x/u, emits B fragment + sender pack + raw x; no
  // loop-carried prefetch registers (R18's spill source).
  auto buildB = [&](int wt_, int n_, unsigned& pks_, bf16x8& Bv_,
                    float& xs0_, float& xs1_) {
    float4 xv_ = (float4){0.f, 0.f, 0.f, 0.f};
    float  uv_ = 0.f;
    if (g == 0) {
      int b = wt_ * 32 + n_ * 8 + (c15 >> 1);
      xv_ = *(const float4*)(x + b * 4);
      uv_ = u[b];
    }
    xs0_ = (c15 & 1) ? xv_.y : xv_.x;   // this row's raw theta
    xs1_ = (c15 & 1) ? xv_.w : xv_.z;   // this row's raw v
    uint4 bu = (uint4){0u, 0u, 0u, 0u};
    if (g == 0) {                       // only k=0..7 nonzero; g==0 lanes hold them
      float a0 = (xv_.x - nm0) * is0, a1 = (xv_.z - nm1) * is1;   // node0
      float b0 = (xv_.y - nm0) * is0, b1 = (xv_.w - nm1) * is1;   // node1
      bool  e  = (c15 & 1);
      float s0 = e ? b0 : a0, s1 = e ? b1 : a1;   // sender feats
      float r0 = e ? a0 : b0, r1 = e ? a1 : b1;   // receiver feats
      float ea0 = (uv_ - em0) * ie0;
      bu.x = cvtpk(s0, s1); bu.y = cvtpk(r0, r1);
      bu.z = cvtpk(ea0, cea1); bu.w = cpkw;
    }
    pks_ = bu.x;
    U4B t; t.u = bu; Bv_ = t.b;
  };

  auto packE = [&](const f32x4 (&a)[8], bf16x8 (&E)[4]) {
    #pragma unroll
    for (int kk = 0; kk < 4; ++kk) {
      f32x4 a0 = a[2 * kk], a1 = a[2 * kk + 1];
      uint4 e;
      e.x = cvtpk(fmaxf(a0[0], 0.f), fmaxf(a0[1], 0.f));
      e.y = cvtpk(fmaxf(a0[2], 0.f), fmaxf(a0[3], 0.f));
      e.z = cvtpk(fmaxf(a1[0], 0.f), fmaxf(a1[1], 0.f));
      e.w = cvtpk(fmaxf(a1[2], 0.f), fmaxf(a1[3], 0.f));
      U4B t; t.u = e; E[kk] = t.b;
    }
  };
  auto packEswap = [&](const f32x4 (&a)[8], bf16x8 (&E)[4]) {
    #pragma unroll
    for (int kk = 0; kk < 4; ++kk) {
      f32x4 a0 = a[2 * kk], a1 = a[2 * kk + 1];
      uint4 e;
      e.x = __shfl_xor(cvtpk(fmaxf(a0[0], 0.f), fmaxf(a0[1], 0.f)), 1, 64);
      e.y = __shfl_xor(cvtpk(fmaxf(a0[2], 0.f), fmaxf(a0[3], 0.f)), 1, 64);
      e.z = __shfl_xor(cvtpk(fmaxf(a1[0], 0.f), fmaxf(a1[1], 0.f)), 1, 64);
      e.w = __shfl_xor(cvtpk(fmaxf(a1[2], 0.f), fmaxf(a1[3], 0.f)), 1, 64);
      U4B t; t.u = e; E[kk] = t.b;
    }
  };

  __syncthreads();   // tables ready — the only barrier

  for (int wt = blockIdx.x * 4 + wid; wt < WTILES; wt += NWAVES) {
    const int rowbase = wt * 64;

    // opaque LDS offset: stop LICM from hoisting table reads into (spilling) registers
    unsigned aoff = 0;
    asm volatile("" : "+v"(aoff));
    const char* aB  = (const char*)aLDS + aoff;
    const char* a2B = (const char*)a2T + aoff;
    const char* a3B = (const char*)a3T + aoff;

    // ---------- build B-operands for all 4 row-groups (tile-local x/u loads) ----------
    unsigned pks[4]; bf16x8 Bv[4];
    float xs0[4], xs1[4];
    #pragma unroll
    for (int n = 0; n < 4; ++n)
      buildB(wt, n, pks[n], Bv[n], xs0[n], xs1[n]);

    f32x4 acc[4][8];

    // ---------- G1: e1 = relu(A1 @ in32); A1 frag shared across n ----------
    #pragma unroll
    for (int m = 0; m < 8; ++m) {
      U4B ta; ta.u = *(const uint4*)(aB + (m * 16 + c15) * 16);   // A1 frag
      #pragma unroll
      for (int n = 0; n < 4; ++n) {
        f32x4 z = (f32x4){0.f, 0.f, 0.f, 0.f};
        acc[n][m] = __builtin_amdgcn_mfma_f32_16x16x32_bf16(ta.b, Bv[n], z, 0, 0, 0);
      }
    }
    bf16x8 E1[4][4];
    #pragma unroll
    for (int n = 0; n < 4; ++n) packE(acc[n], E1[n]);

    // ---------- G2: e2 = relu(A2 @ e1 + be2); A2 from LDS, shared across n ----------
    #pragma unroll
    for (int m = 0; m < 8; ++m) {
      f32x4 bz = *(const f32x4*)(aB + 8192 + (m * 16 + g * 4) * 4);
      #pragma unroll
      for (int n = 0; n < 4; ++n) acc[n][m] = bz;
    }
    #pragma unroll
    for (int kk = 0; kk < 4; ++kk)
      #pragma unroll
      for (int m = 0; m < 8; ++m) {
        U4B tf; tf.u = *(const uint4*)(a2B + (m * 16 + c15) * 256 + ((kk * 64 + g * 16) ^ sw15));
        #pragma unroll
        for (int n = 0; n < 4; ++n)
          acc[n][m] = __builtin_amdgcn_mfma_f32_16x16x32_bf16(tf.b, E1[n][kk], acc[n][m], 0, 0, 0);
      }
    bf16x8 E2[4][4];
    #pragma unroll
    for (int n = 0; n < 4; ++n) packEswap(acc[n], E2[n]);

    // ---------- G3: hdd = relu(A3 @ [e2[r^1]; sender,1]); A3 from LDS, shared ----------
    #pragma unroll
    for (int m = 0; m < 8; ++m)
      #pragma unroll
      for (int n = 0; n < 4; ++n)
        acc[n][m] = (f32x4){0.f, 0.f, 0.f, 0.f};
    #pragma unroll
    for (int kk = 0; kk < 4; ++kk)
      #pragma unroll
      for (int m = 0; m < 8; ++m) {
        U4B tf; tf.u = *(const uint4*)(a3B + (m * 16 + c15) * 256 + ((kk * 64 + g * 16) ^ sw15));
        #pragma unroll
        for (int n = 0; n < 4; ++n)
          acc[n][m] = __builtin_amdgcn_mfma_f32_16x16x32_bf16(tf.b, E2[n][kk], acc[n][m], 0, 0, 0);
      }
    {
      // K-chunk 4: node feats (= sender feats) + const-1 (bn1 column); A3e shared
      U4B t4[4];
      #pragma unroll
      for (int n = 0; n < 4; ++n) {
        uint4 b4 = (uint4){0u, 0u, 0u, 0u};
        if (g == 0) { b4.x = pks[n]; b4.y = 0x00003F80u; }
        t4[n].u = b4;
      }
      #pragma unroll
      for (int m = 0; m < 8; ++m) {
        U4B te; te.u = *(const uint4*)(aB + 2048 + (m * 16 + c15) * 16);  // A3e frag
        #pragma unroll
        for (int n = 0; n < 4; ++n)
          acc[n][m] = __builtin_amdgcn_mfma_f32_16x16x32_bf16(te.b, t4[n].b, acc[n][m], 0, 0, 0);
      }
    }

    // ---------- G4: delta = A4 @ relu(hdd) + bn2; A4 from aLDS (4 reads, shared) ----------
    {
      bf16x8 A4f[4];
      #pragma unroll
      for (int kk = 0; kk < 4; ++kk) {
        U4B ta; ta.u = *(const uint4*)(aB + 4096 + c15 * 256 + kk * 64 + g * 16);
        A4f[kk] = ta.b;
      }
      #pragma unroll
      for (int n = 0; n < 4; ++n) {
        bf16x8 HD[4];
        packE(acc[n], HD);
        f32x4 a4 = (f32x4){0.f, 0.f, 0.f, 0.f};
        #pragma unroll
        for (int kk = 0; kk < 4; ++kk)
          a4 = __builtin_amdgcn_mfma_f32_16x16x32_bf16(A4f[kk], HD[kk], a4, 0, 0, 0);
        if (g == 0) {                  // lane holds delta c0,c1 for row rowbase+n*16+c15
          int gr = rowbase + n * 16 + c15;
          int bidx = gr >> 1, k = gr & 1;
          out[bidx * 4 + k]     = xs0[n] + a4[0] + bn20;
          out[bidx * 4 + k + 2] = xs1[n] + a4[1] + bn21;
        }
      }
    }
    // no barrier: LDS tables are read-only after init; all activations in registers.
  }
}

extern "C" void kernel_launch(void* const* d_in, const int* in_sizes, int n_in,
                              void* d_out, int out_size, void* d_ws, size_t ws_size,
                              hipStream_t stream) {
  const float* x   = (const float*)d_in[0];
  const float* u   = (const float*)d_in[1];
  const float* nm  = (const float*)d_in[2];
  const float* ns  = (const float*)d_in[3];
  const float* em  = (const float*)d_in[4];
  const float* es  = (const float*)d_in[5];
  const float* We1 = (const float*)d_in[6];
  const float* be1 = (const float*)d_in[7];
  const float* We2 = (const float*)d_in[8];
  const float* be2 = (const float*)d_in[9];
  const float* Wn1 = (const float*)d_in[10];
  const float* bn1 = (const float*)d_in[11];
  const float* Wn2 = (const float*)d_in[12];
  const float* bn2 = (const float*)d_in[13];
  unsigned short* wsA = (unsigned short*)d_ws;   // needs 74240 bytes
  float* out = (float*)d_out;

  gn_prep<<<145, 256, 0, stream>>>(We1, be1, We2, Wn1, bn1, Wn2, be2, wsA);
  gn_main<<<512, 256, 0, stream>>>(x, u, nm, ns, em, es, bn2, wsA, out);
}